// Round 6
// baseline (196.177 us; speedup 1.0000x reference)
//
#include <hip/hip_runtime.h>

#define SIM_T 0.8f

typedef float f32x4 __attribute__((ext_vector_type(4)));

__device__ __forceinline__ f32x4 ntload4(const float* p) {
  return __builtin_nontemporal_load(reinterpret_cast<const f32x4*>(p));
}
__device__ __forceinline__ float ntload1(const float* p) {
  return __builtin_nontemporal_load(p);
}

// Fused kernel: per (row, part) masked sum of exp(output[row, 1+k]) with
// cos[row, k] < SIM_T. Last block of each row folds the row's partials into
// rowloss[row]; the last row overall reduces rowloss deterministically and
// writes the mean. Counters (row_cnt, done) are memset to 0 on the stream
// before this launch each call.
// grid = B*parts blocks, 256 threads; per_part = K/parts (multiple of 4096).
__global__ __launch_bounds__(256) void pruner_fused(
    const float* __restrict__ out, const float* __restrict__ cs,
    float* __restrict__ ws_part, float* __restrict__ rowloss,
    int* __restrict__ row_cnt, int* __restrict__ done,
    float* __restrict__ res, int K, int parts, int B) {
  const int per_part = K / parts;          // 8192
  const int row  = blockIdx.x / parts;
  const int part = blockIdx.x % parts;
  const int tid  = threadIdx.x;

  const float* crow = cs  + (size_t)row * K + (size_t)part * per_part;
  const float* orow = out + (size_t)row * (K + 1) + 1 + (size_t)part * per_part;

  float a0 = 0.f, a1 = 0.f, a2 = 0.f, a3 = 0.f;

  for (int kb = tid * 4; kb < per_part; kb += 4096) {
    // ---- issue all loads first (nontemporal: evict-first, use-once) ----
    f32x4 c0 = ntload4(crow + kb);
    f32x4 c1 = ntload4(crow + kb + 1024);
    f32x4 c2 = ntload4(crow + kb + 2048);
    f32x4 c3 = ntload4(crow + kb + 3072);
    float x00 = ntload1(orow + kb +    0), x01 = ntload1(orow + kb +    1);
    float x02 = ntload1(orow + kb +    2), x03 = ntload1(orow + kb +    3);
    float x10 = ntload1(orow + kb + 1024), x11 = ntload1(orow + kb + 1025);
    float x12 = ntload1(orow + kb + 1026), x13 = ntload1(orow + kb + 1027);
    float x20 = ntload1(orow + kb + 2048), x21 = ntload1(orow + kb + 2049);
    float x22 = ntload1(orow + kb + 2050), x23 = ntload1(orow + kb + 2051);
    float x30 = ntload1(orow + kb + 3072), x31 = ntload1(orow + kb + 3073);
    float x32 = ntload1(orow + kb + 3074), x33 = ntload1(orow + kb + 3075);
    // ---- then compute ----
    a0 += (c0.x < SIM_T) ? __expf(x00) : 0.f;
    a1 += (c0.y < SIM_T) ? __expf(x01) : 0.f;
    a2 += (c0.z < SIM_T) ? __expf(x02) : 0.f;
    a3 += (c0.w < SIM_T) ? __expf(x03) : 0.f;
    a0 += (c1.x < SIM_T) ? __expf(x10) : 0.f;
    a1 += (c1.y < SIM_T) ? __expf(x11) : 0.f;
    a2 += (c1.z < SIM_T) ? __expf(x12) : 0.f;
    a3 += (c1.w < SIM_T) ? __expf(x13) : 0.f;
    a0 += (c2.x < SIM_T) ? __expf(x20) : 0.f;
    a1 += (c2.y < SIM_T) ? __expf(x21) : 0.f;
    a2 += (c2.z < SIM_T) ? __expf(x22) : 0.f;
    a3 += (c2.w < SIM_T) ? __expf(x23) : 0.f;
    a0 += (c3.x < SIM_T) ? __expf(x30) : 0.f;
    a1 += (c3.y < SIM_T) ? __expf(x31) : 0.f;
    a2 += (c3.z < SIM_T) ? __expf(x32) : 0.f;
    a3 += (c3.w < SIM_T) ? __expf(x33) : 0.f;
  }
  float s = (a0 + a1) + (a2 + a3);

#pragma unroll
  for (int off = 32; off > 0; off >>= 1) s += __shfl_down(s, off, 64);

  __shared__ float lds[4];
  if ((tid & 63) == 0) lds[tid >> 6] = s;
  __syncthreads();

  if (tid == 0) {
    const float st = (lds[0] + lds[1]) + (lds[2] + lds[3]);
    ws_part[blockIdx.x] = st;
    __threadfence();
    const int old = atomicAdd(&row_cnt[row], 1);
    if (old == parts - 1) {
      // last block of this row: fold the row (reads are L2-hot)
      __threadfence();
      float t = 0.f;
      for (int p = 0; p < parts; ++p) t += ws_part[row * parts + p];
      const float o0 = out[(size_t)row * (K + 1)];
      t += __expf(o0);
      rowloss[row] = logf(t) - o0;
      __threadfence();
      const int old2 = atomicAdd(done, 1);
      if (old2 == B - 1) {
        // last row overall: deterministic fixed-order reduction of B losses
        __threadfence();
        float r0 = 0.f, r1 = 0.f, r2 = 0.f, r3 = 0.f;
        int r = 0;
        for (; r + 4 <= B; r += 4) {
          r0 += rowloss[r + 0];
          r1 += rowloss[r + 1];
          r2 += rowloss[r + 2];
          r3 += rowloss[r + 3];
        }
        float tot = (r0 + r1) + (r2 + r3);
        for (; r < B; ++r) tot += rowloss[r];
        res[0] = tot / (float)B;
      }
    }
  }
}

// Generic fallback for shapes where per_part % 4096 != 0 (2-kernel path).
__global__ __launch_bounds__(256) void pruner_partial_simple(
    const float* __restrict__ out, const float* __restrict__ cs,
    float* __restrict__ ws, int K, int parts) {
  const int per_part = K / parts;
  const int row  = blockIdx.x / parts;
  const int part = blockIdx.x % parts;
  const int tid  = threadIdx.x;
  const float* crow = cs  + (size_t)row * K + (size_t)part * per_part;
  const float* orow = out + (size_t)row * (K + 1) + 1 + (size_t)part * per_part;
  float a = 0.f;
  for (int k = tid; k < per_part; k += 256)
    a += (crow[k] < SIM_T) ? __expf(orow[k]) : 0.f;
#pragma unroll
  for (int off = 32; off > 0; off >>= 1) a += __shfl_down(a, off, 64);
  __shared__ float lds[4];
  if ((tid & 63) == 0) lds[tid >> 6] = a;
  __syncthreads();
  if (tid == 0) ws[blockIdx.x] = (lds[0] + lds[1]) + (lds[2] + lds[3]);
}

__global__ __launch_bounds__(256) void pruner_final_simple(
    const float* __restrict__ out, const float* __restrict__ ws,
    float* __restrict__ res, int K, int parts, int B) {
  const int i = threadIdx.x;  // row
  float loss = 0.0f;
  if (i < B) {
    float t = 0.0f;
    for (int p = 0; p < parts; ++p) t += ws[i * parts + p];
    const float o0 = out[(size_t)i * (K + 1)];
    t += __expf(o0);
    loss = logf(t) - o0;
  }
#pragma unroll
  for (int off = 32; off > 0; off >>= 1) loss += __shfl_down(loss, off, 64);
  __shared__ float lds[4];
  if ((i & 63) == 0) lds[i >> 6] = loss;
  __syncthreads();
  if (i == 0) res[0] = ((lds[0] + lds[1]) + (lds[2] + lds[3])) / (float)B;
}

extern "C" void kernel_launch(void* const* d_in, const int* in_sizes, int n_in,
                              void* d_out, int out_size, void* d_ws, size_t ws_size,
                              hipStream_t stream) {
  const float* out = (const float*)d_in[0];   // [B, K+1] f32
  const float* cs  = (const float*)d_in[1];   // [B, K]   f32
  float* res = (float*)d_out;                 // scalar f32

  const int B = in_sizes[2];                  // 256
  const int K = in_sizes[1] / B;              // 65536
  const int PARTS = 8;                        // 2048 blocks = 8/CU

  // workspace layout
  float* ws_part = (float*)d_ws;                       // [B*PARTS] partials
  float* rowloss = ws_part + (size_t)B * PARTS;        // [B] row losses
  int*   ctrs    = (int*)((char*)d_ws + 32768);        // [B] row_cnt + [1] done
  int*   row_cnt = ctrs;
  int*   done    = ctrs + B;

  if ((K / PARTS) % 4096 == 0 && B <= 4096) {
    hipMemsetAsync(ctrs, 0, (size_t)(B + 1) * sizeof(int), stream);
    pruner_fused<<<B * PARTS, 256, 0, stream>>>(out, cs, ws_part, rowloss,
                                                row_cnt, done, res, K, PARTS, B);
  } else {
    pruner_partial_simple<<<B * PARTS, 256, 0, stream>>>(out, cs, ws_part, K, PARTS);
    pruner_final_simple<<<1, 256, 0, stream>>>(out, ws_part, res, K, PARTS, B);
  }
}

// Round 7
// 26.521 us; speedup vs baseline: 7.3969x; 7.3969x over previous
//
#include <hip/hip_runtime.h>

#define SIM_T 0.8f

typedef float f32x4 __attribute__((ext_vector_type(4)));

__device__ __forceinline__ f32x4 ntload4(const float* p) {
  return __builtin_nontemporal_load(reinterpret_cast<const f32x4*>(p));
}
__device__ __forceinline__ float ntload1(const float* p) {
  return __builtin_nontemporal_load(p);
}

// Kernel 1: per (row, part) masked sum of exp(output[row, 1+k]) over the
// part's slice, keeping only k where cos[row, k] < SIM_T.
// Best-known structure (R5, 26.2 us): nt loads (streaming, use-once data),
// 4x-unrolled issue-first loop, o0 staging so the final kernel reads
// coalesced. Fusion via device-scope atomics/fences was tried and REGRESSED
// 7.5x (per-XCD L2 writeback/invalidate storm) — keep two dispatches.
// grid = B*parts blocks, 256 threads; per_part = K/parts (multiple of 4096).
__global__ __launch_bounds__(256) void pruner_partial(
    const float* __restrict__ out, const float* __restrict__ cs,
    float* __restrict__ ws, float* __restrict__ o0s, int K, int parts) {
  const int per_part = K / parts;          // 8192
  const int row  = blockIdx.x / parts;
  const int part = blockIdx.x % parts;
  const int tid  = threadIdx.x;

  const float* crow = cs  + (size_t)row * K + (size_t)part * per_part;
  const float* orow = out + (size_t)row * (K + 1) + 1 + (size_t)part * per_part;

  // stage the positive logit for the final kernel (coalesced there)
  if (part == 0 && tid == 0) o0s[row] = orow[-1];

  float a0 = 0.f, a1 = 0.f, a2 = 0.f, a3 = 0.f;

  for (int kb = tid * 4; kb < per_part; kb += 4096) {
    // ---- issue all loads first (nontemporal: evict-first, use-once) ----
    f32x4 c0 = ntload4(crow + kb);
    f32x4 c1 = ntload4(crow + kb + 1024);
    f32x4 c2 = ntload4(crow + kb + 2048);
    f32x4 c3 = ntload4(crow + kb + 3072);
    float x00 = ntload1(orow + kb +    0), x01 = ntload1(orow + kb +    1);
    float x02 = ntload1(orow + kb +    2), x03 = ntload1(orow + kb +    3);
    float x10 = ntload1(orow + kb + 1024), x11 = ntload1(orow + kb + 1025);
    float x12 = ntload1(orow + kb + 1026), x13 = ntload1(orow + kb + 1027);
    float x20 = ntload1(orow + kb + 2048), x21 = ntload1(orow + kb + 2049);
    float x22 = ntload1(orow + kb + 2050), x23 = ntload1(orow + kb + 2051);
    float x30 = ntload1(orow + kb + 3072), x31 = ntload1(orow + kb + 3073);
    float x32 = ntload1(orow + kb + 3074), x33 = ntload1(orow + kb + 3075);
    // ---- then compute ----
    a0 += (c0.x < SIM_T) ? __expf(x00) : 0.f;
    a1 += (c0.y < SIM_T) ? __expf(x01) : 0.f;
    a2 += (c0.z < SIM_T) ? __expf(x02) : 0.f;
    a3 += (c0.w < SIM_T) ? __expf(x03) : 0.f;
    a0 += (c1.x < SIM_T) ? __expf(x10) : 0.f;
    a1 += (c1.y < SIM_T) ? __expf(x11) : 0.f;
    a2 += (c1.z < SIM_T) ? __expf(x12) : 0.f;
    a3 += (c1.w < SIM_T) ? __expf(x13) : 0.f;
    a0 += (c2.x < SIM_T) ? __expf(x20) : 0.f;
    a1 += (c2.y < SIM_T) ? __expf(x21) : 0.f;
    a2 += (c2.z < SIM_T) ? __expf(x22) : 0.f;
    a3 += (c2.w < SIM_T) ? __expf(x23) : 0.f;
    a0 += (c3.x < SIM_T) ? __expf(x30) : 0.f;
    a1 += (c3.y < SIM_T) ? __expf(x31) : 0.f;
    a2 += (c3.z < SIM_T) ? __expf(x32) : 0.f;
    a3 += (c3.w < SIM_T) ? __expf(x33) : 0.f;
  }
  float s = (a0 + a1) + (a2 + a3);

#pragma unroll
  for (int off = 32; off > 0; off >>= 1) s += __shfl_down(s, off, 64);

  __shared__ float lds[4];
  if ((tid & 63) == 0) lds[tid >> 6] = s;
  __syncthreads();
  if (tid == 0) ws[blockIdx.x] = (lds[0] + lds[1]) + (lds[2] + lds[3]);
}

// Generic fallback for shapes where per_part % 4096 != 0.
__global__ __launch_bounds__(256) void pruner_partial_simple(
    const float* __restrict__ out, const float* __restrict__ cs,
    float* __restrict__ ws, float* __restrict__ o0s, int K, int parts) {
  const int per_part = K / parts;
  const int row  = blockIdx.x / parts;
  const int part = blockIdx.x % parts;
  const int tid  = threadIdx.x;
  const float* crow = cs  + (size_t)row * K + (size_t)part * per_part;
  const float* orow = out + (size_t)row * (K + 1) + 1 + (size_t)part * per_part;
  if (part == 0 && tid == 0) o0s[row] = orow[-1];
  float a = 0.f;
  for (int k = tid; k < per_part; k += 256)
    a += (crow[k] < SIM_T) ? __expf(orow[k]) : 0.f;
#pragma unroll
  for (int off = 32; off > 0; off >>= 1) a += __shfl_down(a, off, 64);
  __shared__ float lds[4];
  if ((tid & 63) == 0) lds[tid >> 6] = a;
  __syncthreads();
  if (tid == 0) ws[blockIdx.x] = (lds[0] + lds[1]) + (lds[2] + lds[3]);
}

// Kernel 2: one block of B threads; everything it reads is coalesced
// (partials + staged o0). Thread i -> row i; block-reduce the mean.
__global__ __launch_bounds__(256) void pruner_final(
    const float* __restrict__ ws, const float* __restrict__ o0s,
    float* __restrict__ res, int parts, int B) {
  const int i = threadIdx.x;  // row
  float loss = 0.0f;
  if (i < B) {
    float t = 0.0f;
    for (int p = 0; p < parts; ++p) t += ws[i * parts + p];
    const float o0 = o0s[i];
    t += __expf(o0);
    loss = logf(t) - o0;
  }
#pragma unroll
  for (int off = 32; off > 0; off >>= 1) loss += __shfl_down(loss, off, 64);
  __shared__ float lds[4];
  if ((i & 63) == 0) lds[i >> 6] = loss;
  __syncthreads();
  if (i == 0) res[0] = ((lds[0] + lds[1]) + (lds[2] + lds[3])) / (float)B;
}

extern "C" void kernel_launch(void* const* d_in, const int* in_sizes, int n_in,
                              void* d_out, int out_size, void* d_ws, size_t ws_size,
                              hipStream_t stream) {
  const float* out = (const float*)d_in[0];   // [B, K+1] f32
  const float* cs  = (const float*)d_in[1];   // [B, K]   f32
  float* res = (float*)d_out;                 // scalar f32

  const int B = in_sizes[2];                  // 256
  const int K = in_sizes[1] / B;              // 65536

  const int PARTS = 8;                        // 2048 blocks = 8/CU
  float* ws  = (float*)d_ws;                  // [B*PARTS] partials
  float* o0s = ws + (size_t)B * PARTS;        // [B] staged positive logits

  if ((K / PARTS) % 4096 == 0) {
    pruner_partial<<<B * PARTS, 256, 0, stream>>>(out, cs, ws, o0s, K, PARTS);
  } else {
    pruner_partial_simple<<<B * PARTS, 256, 0, stream>>>(out, cs, ws, o0s, K, PARTS);
  }
  pruner_final<<<1, 256, 0, stream>>>(ws, o0s, res, PARTS, B);
}